// Round 1
// baseline (534.244 us; speedup 1.0000x reference)
//
#include <hip/hip_runtime.h>
#include <hip/hip_bf16.h>

// Problem constants
#define BATCH 8
#define CCH   384      // channels C == INNER
#define NTOK  1024     // H*W
#define HEADS 6
#define DHEAD 64
#define SCALE 0.125f   // 1/sqrt(64)

// ---------------------------------------------------------------------------
// Generic fp32 GEMM: Y[b][m][n] = sum_k W[m][k] * X[b][k][n] (+ bias[m])
// M=384, K=384, N=1024. Tile 64x64, 256 threads, 4x4 per thread.
// ---------------------------------------------------------------------------
#define KT 16
#define LDP 68   // LDS pad: multiple of 4 (keeps float4 alignment), breaks 64-stride

__global__ __launch_bounds__(256) void gemm_wx(
    const float* __restrict__ W,   // [M, K] row-major
    const float* __restrict__ X,   // [Bz, K, N]
    float* __restrict__ Y,         // [Bz, M, N]
    const float* __restrict__ bias,
    int M, int K, int N)
{
    const int bz = blockIdx.z;
    const int m0 = blockIdx.y * 64;
    const int n0 = blockIdx.x * 64;
    const float* Xb = X + (size_t)bz * K * N;
    float* Yb       = Y + (size_t)bz * M * N;

    __shared__ float As[KT][LDP];  // [k][m]  (W tile transposed)
    __shared__ float Bs[KT][LDP];  // [k][n]

    const int tid = threadIdx.x;
    const int tx = tid & 15, ty = tid >> 4;

    float acc[4][4] = {};

    for (int k0 = 0; k0 < K; k0 += KT) {
        // W tile: 64 m x 16 k. thread: m = tid>>2, k = (tid&3)*4 .. +3
        {
            const int m  = tid >> 2;
            const int kk = (tid & 3) * 4;
            const float4 w4 = *(const float4*)&W[(size_t)(m0 + m) * K + k0 + kk];
            As[kk + 0][m] = w4.x;
            As[kk + 1][m] = w4.y;
            As[kk + 2][m] = w4.z;
            As[kk + 3][m] = w4.w;
            // X tile: 16 k x 64 n. thread: k = tid>>4, n = (tid&15)*4
            const int kx = tid >> 4;
            const int nn = (tid & 15) * 4;
            *(float4*)&Bs[kx][nn] =
                *(const float4*)&Xb[(size_t)(k0 + kx) * N + n0 + nn];
        }
        __syncthreads();
#pragma unroll
        for (int kk = 0; kk < KT; ++kk) {
            float a[4], bb[4];
            *(float4*)a  = *(const float4*)&As[kk][ty * 4];
            *(float4*)bb = *(const float4*)&Bs[kk][tx * 4];
#pragma unroll
            for (int i = 0; i < 4; ++i)
#pragma unroll
                for (int j = 0; j < 4; ++j)
                    acc[i][j] = fmaf(a[i], bb[j], acc[i][j]);
        }
        __syncthreads();
    }

#pragma unroll
    for (int i = 0; i < 4; ++i) {
        const int m = m0 + ty * 4 + i;
        const float bv = bias ? bias[m] : 0.0f;
        float4 o;
        o.x = acc[i][0] + bv; o.y = acc[i][1] + bv;
        o.z = acc[i][2] + bv; o.w = acc[i][3] + bv;
        *(float4*)&Yb[(size_t)m * N + n0 + tx * 4] = o;
    }
}

// ---------------------------------------------------------------------------
// Fused attention per (b, head, i-tile of 64 queries).
// q,k,v: [B*HEADS, 64, 1024] (d-major rows, token-contiguous).
// Pass 1: den_i = sum_j exp(scale * S_ij)   (no max-subtraction: |logit| <~ 1)
// Pass 2: recompute exp, P = e/den, O[d,i] += P·V, colsum -> attn_map atomics
// ---------------------------------------------------------------------------
__global__ __launch_bounds__(256) void attn_kernel(
    const float* __restrict__ q,
    const float* __restrict__ k,
    const float* __restrict__ v,
    float* __restrict__ omid,      // [B*HEADS, 64, 1024]
    float* __restrict__ attn_map)  // [B, 1024], pre-zeroed
{
    const int bh = blockIdx.y;           // 0..47
    const int b  = bh / HEADS;
    const int i0 = blockIdx.x * 64;

    const float* Q = q + (size_t)bh * DHEAD * NTOK;
    const float* K = k + (size_t)bh * DHEAD * NTOK;
    const float* V = v + (size_t)bh * DHEAD * NTOK;

    __shared__ float Qs[64][LDP];
    __shared__ float Ks[64][LDP];
    __shared__ float Vs[64][LDP];
    __shared__ float Ps[64][LDP];
    __shared__ float rdenl[64];
    __shared__ float red[16][LDP];   // reused: den reduce [16][64], colsum [4][64]

    const int tid = threadIdx.x;
    const int tx = tid & 15, ty = tid >> 4;

    // Load Q tile [d][i]: 64x64
#pragma unroll
    for (int r = 0; r < 4; ++r) {
        const int d  = r * 16 + ty;
        const int ii = tx * 4;
        *(float4*)&Qs[d][ii] = *(const float4*)&Q[(size_t)d * NTOK + i0 + ii];
    }

    // ---------------- Pass 1: denominators ----------------
    float denp[4] = {0.f, 0.f, 0.f, 0.f};
    for (int jt = 0; jt < 16; ++jt) {
        const int j0 = jt * 64;
        __syncthreads();   // prior reads of Ks done; Qs visible on first iter
#pragma unroll
        for (int r = 0; r < 4; ++r) {
            const int d  = r * 16 + ty;
            const int jj = tx * 4;
            *(float4*)&Ks[d][jj] = *(const float4*)&K[(size_t)d * NTOK + j0 + jj];
        }
        __syncthreads();
        float s[4][4] = {};
#pragma unroll 8
        for (int d = 0; d < 64; ++d) {
            float a[4], bb[4];
            *(float4*)a  = *(const float4*)&Qs[d][ty * 4];
            *(float4*)bb = *(const float4*)&Ks[d][tx * 4];
#pragma unroll
            for (int i = 0; i < 4; ++i)
#pragma unroll
                for (int j = 0; j < 4; ++j)
                    s[i][j] = fmaf(a[i], bb[j], s[i][j]);
        }
#pragma unroll
        for (int i = 0; i < 4; ++i)
#pragma unroll
            for (int j = 0; j < 4; ++j)
                denp[i] += __expf(s[i][j] * SCALE);
    }
    __syncthreads();
#pragma unroll
    for (int i = 0; i < 4; ++i) red[tx][ty * 4 + i] = denp[i];
    __syncthreads();
    if (tid < 64) {
        float ssum = 0.f;
#pragma unroll
        for (int t = 0; t < 16; ++t) ssum += red[t][tid];
        rdenl[tid] = 1.0f / ssum;
    }
    __syncthreads();
    float rden[4];
#pragma unroll
    for (int i = 0; i < 4; ++i) rden[i] = rdenl[ty * 4 + i];

    // ---------------- Pass 2: P = e/den, O = P·V, colsums ----------------
    float oacc[4][4] = {};   // [dd][ii]: d = ty + 16*dd, i = tx + 16*ii
    for (int jt = 0; jt < 16; ++jt) {
        const int j0 = jt * 64;
        __syncthreads();   // prior PV reads + colsum finalize done
#pragma unroll
        for (int r = 0; r < 4; ++r) {
            const int d  = r * 16 + ty;
            const int jj = tx * 4;
            *(float4*)&Ks[d][jj] = *(const float4*)&K[(size_t)d * NTOK + j0 + jj];
            *(float4*)&Vs[d][jj] = *(const float4*)&V[(size_t)d * NTOK + j0 + jj];
        }
        __syncthreads();
        float s[4][4] = {};
#pragma unroll 8
        for (int d = 0; d < 64; ++d) {
            float a[4], bb[4];
            *(float4*)a  = *(const float4*)&Qs[d][ty * 4];
            *(float4*)bb = *(const float4*)&Ks[d][tx * 4];
#pragma unroll
            for (int i = 0; i < 4; ++i)
#pragma unroll
                for (int j = 0; j < 4; ++j)
                    s[i][j] = fmaf(a[i], bb[j], s[i][j]);
        }
#pragma unroll
        for (int i = 0; i < 4; ++i) {
            float4 pv;
            pv.x = __expf(s[i][0] * SCALE) * rden[i];
            pv.y = __expf(s[i][1] * SCALE) * rden[i];
            pv.z = __expf(s[i][2] * SCALE) * rden[i];
            pv.w = __expf(s[i][3] * SCALE) * rden[i];
            *(float4*)&Ps[ty * 4 + i][tx * 4] = pv;
        }
        __syncthreads();
        // PV: vectorize over j (b128 reads from Ps rows i=tx+16ii, Vs rows d=ty+16dd)
#pragma unroll 4
        for (int j4 = 0; j4 < 64; j4 += 4) {
            float pf[4][4], vf[4][4];
#pragma unroll
            for (int i = 0; i < 4; ++i)
                *(float4*)pf[i] = *(const float4*)&Ps[tx + 16 * i][j4];
#pragma unroll
            for (int d = 0; d < 4; ++d)
                *(float4*)vf[d] = *(const float4*)&Vs[ty + 16 * d][j4];
#pragma unroll
            for (int d = 0; d < 4; ++d)
#pragma unroll
                for (int i = 0; i < 4; ++i)
#pragma unroll
                    for (int j = 0; j < 4; ++j)
                        oacc[d][i] = fmaf(pf[i][j], vf[d][j], oacc[d][i]);
        }
        // colsum partials: thread sums 16 rows of its column
        {
            const int j  = tid & 63;
            const int qd = tid >> 6;
            float cs = 0.f;
#pragma unroll
            for (int r = 0; r < 16; ++r) cs += Ps[qd * 16 + r][j];
            red[qd][j] = cs;
        }
        __syncthreads();
        if (tid < 64) {
            const float t = red[0][tid] + red[1][tid] + red[2][tid] + red[3][tid];
            atomicAdd(&attn_map[(size_t)b * NTOK + j0 + tid],
                      t * (1.0f / (HEADS * NTOK)));
        }
    }

    // Store O tile: omid[bh*64 + d][i0 + i]
#pragma unroll
    for (int d = 0; d < 4; ++d)
#pragma unroll
        for (int i = 0; i < 4; ++i)
            omid[((size_t)bh * 64 + ty + 16 * d) * NTOK + i0 + tx + 16 * i] =
                oacc[d][i];
}

// ---------------------------------------------------------------------------
extern "C" void kernel_launch(void* const* d_in, const int* in_sizes, int n_in,
                              void* d_out, int out_size, void* d_ws, size_t ws_size,
                              hipStream_t stream)
{
    const float* query   = (const float*)d_in[0];
    const float* context = (const float*)d_in[1];
    const float* Wq      = (const float*)d_in[2];
    const float* Wk      = (const float*)d_in[3];
    const float* Wv      = (const float*)d_in[4];
    const float* Wo      = (const float*)d_in[5];
    const float* bo      = (const float*)d_in[6];

    float* out = (float*)d_out;                              // [8, 384, 1024]
    const size_t out_elems = (size_t)BATCH * CCH * NTOK;     // 3,145,728
    float* attn_map = out + out_elems;                       // [8, 1024]

    float* ws   = (float*)d_ws;
    const size_t slab = (size_t)BATCH * CCH * NTOK;          // 3,145,728 floats
    float* wsq = ws;
    float* wsk = ws + slab;
    float* wsv = ws + 2 * slab;
    float* wsm = ws + 3 * slab;

    // attn_map is accumulated with atomics -> zero it (d_out is 0xAA-poisoned)
    hipMemsetAsync(attn_map, 0, (size_t)BATCH * NTOK * sizeof(float), stream);

    const dim3 gblk(256);
    const dim3 ggrid(NTOK / 64, CCH / 64, BATCH);

    gemm_wx<<<ggrid, gblk, 0, stream>>>(Wq, query,   wsq, nullptr, CCH, CCH, NTOK);
    gemm_wx<<<ggrid, gblk, 0, stream>>>(Wk, context, wsk, nullptr, CCH, CCH, NTOK);
    gemm_wx<<<ggrid, gblk, 0, stream>>>(Wv, context, wsv, nullptr, CCH, CCH, NTOK);

    const dim3 agrid(NTOK / 64, BATCH * HEADS);
    attn_kernel<<<agrid, gblk, 0, stream>>>(wsq, wsk, wsv, wsm, attn_map);

    gemm_wx<<<ggrid, gblk, 0, stream>>>(Wo, wsm, out, bo, CCH, CCH, NTOK);
}

// Round 2
// 312.279 us; speedup vs baseline: 1.7108x; 1.7108x over previous
//
#include <hip/hip_runtime.h>

// Problem constants
#define BATCH 8
#define CCH   384      // channels C == INNER
#define NTOK  1024     // H*W
#define HEADS 6
#define DHEAD 64
#define SCALE 0.125f   // 1/sqrt(64)

typedef __bf16 bf16x8 __attribute__((ext_vector_type(8)));
typedef float  f32x4  __attribute__((ext_vector_type(4)));

#define MFMA16(a, b, c) __builtin_amdgcn_mfma_f32_16x16x32_bf16((a), (b), (c), 0, 0, 0)

// fp32 -> bf16 RNE, as raw bits
__device__ __forceinline__ short f2b(float x) {
    unsigned u = __float_as_uint(x);
    u += 0x7fffu + ((u >> 16) & 1u);
    return (short)(u >> 16);
}

// ---------------------------------------------------------------------------
// Transpose+convert: X[b][C][N] fp32 -> Xt[b][N][C] bf16
// grid (N/64, C/64, B), 256 threads
// ---------------------------------------------------------------------------
__global__ __launch_bounds__(256) void xpose_cvt(
    const float* __restrict__ X, short* __restrict__ Xt)
{
    __shared__ float tile[64][65];
    const int tid = threadIdx.x;
    const int b = blockIdx.z, n0 = blockIdx.x * 64, c0 = blockIdx.y * 64;
    const int tx = tid & 15, ty = tid >> 4;
#pragma unroll
    for (int rr = 0; rr < 4; ++rr) {
        const int c = rr * 16 + ty;
        float4 v = *(const float4*)&X[((size_t)(b * CCH + c0 + c)) * NTOK + n0 + tx * 4];
        tile[c][tx * 4 + 0] = v.x; tile[c][tx * 4 + 1] = v.y;
        tile[c][tx * 4 + 2] = v.z; tile[c][tx * 4 + 3] = v.w;
    }
    __syncthreads();
    const int n = tid >> 2, cb = (tid & 3) * 16;
    short tmp[16];
#pragma unroll
    for (int cc = 0; cc < 16; ++cc) tmp[cc] = f2b(tile[cb + cc][n]);
    short* dst = &Xt[((size_t)(b * NTOK + n0 + n)) * CCH + c0 + cb];
    *(int4*)dst = *(int4*)&tmp[0];
    *(int4*)(dst + 8) = *(int4*)&tmp[8];
}

// ---------------------------------------------------------------------------
// Convert 4 weight matrices fp32 -> bf16 (flat). grid (144, 4), 256 threads
// ---------------------------------------------------------------------------
__global__ __launch_bounds__(256) void convert_w(
    const float* __restrict__ w0, const float* __restrict__ w1,
    const float* __restrict__ w2, const float* __restrict__ w3,
    short* __restrict__ o0, short* __restrict__ o1,
    short* __restrict__ o2, short* __restrict__ o3)
{
    const int idx = blockIdx.x * 256 + threadIdx.x;   // 0..36863 (x4 floats)
    const int which = blockIdx.y;
    const float* s = which == 0 ? w0 : which == 1 ? w1 : which == 2 ? w2 : w3;
    short* d       = which == 0 ? o0 : which == 1 ? o1 : which == 2 ? o2 : o3;
    float4 v = ((const float4*)s)[idx];
    short4 o = make_short4(f2b(v.x), f2b(v.y), f2b(v.z), f2b(v.w));
    ((short4*)d)[idx] = o;
}

// ---------------------------------------------------------------------------
// GEMM, token-major output: Yt[b][tok][ch] = sum_k Xt[b][tok][k] * W[ch][k]
// grid (16 tok-tiles, 6 ch-tiles, B). All MFMA frags direct from global.
// ---------------------------------------------------------------------------
__global__ __launch_bounds__(256) void gemm_tmaj(
    const short* __restrict__ Xt, const short* __restrict__ W,
    short* __restrict__ Yt)
{
    const int tid = threadIdx.x, l15 = tid & 15, quad = (tid >> 4) & 3, wv = tid >> 6;
    const int b = blockIdx.z, t0 = blockIdx.x * 64, c0 = blockIdx.y * 64;
    const short* arow = Xt + ((size_t)(b * NTOK + t0 + wv * 16 + l15)) * CCH + quad * 8;
    f32x4 acc[4] = {{0,0,0,0},{0,0,0,0},{0,0,0,0},{0,0,0,0}};
#pragma unroll 4
    for (int kc = 0; kc < 12; ++kc) {
        bf16x8 a = *(const bf16x8*)(arow + kc * 32);
#pragma unroll
        for (int ns = 0; ns < 4; ++ns) {
            const short* bp = W + ((size_t)(c0 + ns * 16 + l15)) * CCH + kc * 32 + quad * 8;
            bf16x8 bb = *(const bf16x8*)bp;
            acc[ns] = MFMA16(a, bb, acc[ns]);
        }
    }
#pragma unroll
    for (int ns = 0; ns < 4; ++ns)
#pragma unroll
        for (int r = 0; r < 4; ++r) {
            const int tok = t0 + wv * 16 + quad * 4 + r;
            Yt[((size_t)(b * NTOK + tok)) * CCH + c0 + ns * 16 + l15] = f2b(acc[ns][r]);
        }
}

// ---------------------------------------------------------------------------
// GEMM, channel-major bf16 output: Y[b][ch][tok] = sum_k W[ch][k] * Xt[b][tok][k]
// ---------------------------------------------------------------------------
__global__ __launch_bounds__(256) void gemm_cmaj_bf16(
    const short* __restrict__ W, const short* __restrict__ Xt,
    short* __restrict__ Y)
{
    const int tid = threadIdx.x, l15 = tid & 15, quad = (tid >> 4) & 3, wv = tid >> 6;
    const int b = blockIdx.z, n0 = blockIdx.x * 64, m0 = blockIdx.y * 64;
    const short* arow = W + ((size_t)(m0 + wv * 16 + l15)) * CCH + quad * 8;
    f32x4 acc[4] = {{0,0,0,0},{0,0,0,0},{0,0,0,0},{0,0,0,0}};
#pragma unroll 4
    for (int kc = 0; kc < 12; ++kc) {
        bf16x8 a = *(const bf16x8*)(arow + kc * 32);
#pragma unroll
        for (int ns = 0; ns < 4; ++ns) {
            const short* bp = Xt + ((size_t)(b * NTOK + n0 + ns * 16 + l15)) * CCH + kc * 32 + quad * 8;
            bf16x8 bb = *(const bf16x8*)bp;
            acc[ns] = MFMA16(a, bb, acc[ns]);
        }
    }
#pragma unroll
    for (int ns = 0; ns < 4; ++ns)
#pragma unroll
        for (int r = 0; r < 4; ++r) {
            const int ch = m0 + wv * 16 + quad * 4 + r;
            Y[((size_t)(b * CCH + ch)) * NTOK + n0 + ns * 16 + l15] = f2b(acc[ns][r]);
        }
}

// ---------------------------------------------------------------------------
// GEMM, channel-major fp32 output + bias (final projection)
// ---------------------------------------------------------------------------
__global__ __launch_bounds__(256) void gemm_cmaj_f32(
    const short* __restrict__ W, const short* __restrict__ Xt,
    const float* __restrict__ bias, float* __restrict__ Y)
{
    const int tid = threadIdx.x, l15 = tid & 15, quad = (tid >> 4) & 3, wv = tid >> 6;
    const int b = blockIdx.z, n0 = blockIdx.x * 64, m0 = blockIdx.y * 64;
    const short* arow = W + ((size_t)(m0 + wv * 16 + l15)) * CCH + quad * 8;
    f32x4 acc[4] = {{0,0,0,0},{0,0,0,0},{0,0,0,0},{0,0,0,0}};
#pragma unroll 4
    for (int kc = 0; kc < 12; ++kc) {
        bf16x8 a = *(const bf16x8*)(arow + kc * 32);
#pragma unroll
        for (int ns = 0; ns < 4; ++ns) {
            const short* bp = Xt + ((size_t)(b * NTOK + n0 + ns * 16 + l15)) * CCH + kc * 32 + quad * 8;
            bf16x8 bb = *(const bf16x8*)bp;
            acc[ns] = MFMA16(a, bb, acc[ns]);
        }
    }
#pragma unroll
    for (int ns = 0; ns < 4; ++ns)
#pragma unroll
        for (int r = 0; r < 4; ++r) {
            const int ch = m0 + wv * 16 + quad * 4 + r;
            Y[((size_t)(b * CCH + ch)) * NTOK + n0 + ns * 16 + l15] = acc[ns][r] + bias[ch];
        }
}

// ---------------------------------------------------------------------------
// Fused attention, MFMA. One block = one (b,h, 64-query i-tile). 4 waves.
// qt, kt: [B][N][C] token-major bf16 (head slice: cols h*64..h*64+63)
// vc:     [B][C][N] channel-major bf16
// Pass 1: den_i = sum_j exp(S_ij*scale)   (no max-sub: |logit| <~ 1)
// Pass 2: recompute S, e; colsum via shfl; P->LDS transpose; PV MFMA;
//         O normalized by rden at store.
// ---------------------------------------------------------------------------
__global__ __launch_bounds__(256) void attn(
    const short* __restrict__ qt, const short* __restrict__ kt,
    const short* __restrict__ vc, short* __restrict__ omid,
    float* __restrict__ amap)
{
    __shared__ short Pst[4][16][72];   // per-wave P strip [i16][j64+pad], 16B-aligned rows
    __shared__ float cmap[4][1024];    // per-wave column-sum accumulators

    const int tid = threadIdx.x, l15 = tid & 15, quad = (tid >> 4) & 3, wv = tid >> 6;
    const int bh = blockIdx.y, b = bh / HEADS, h = bh % HEADS;
    const int i0 = blockIdx.x * 64;

    for (int idx = tid; idx < 4096; idx += 256) (&cmap[0][0])[idx] = 0.f;
    __syncthreads();

    const size_t hoff = (size_t)b * NTOK * CCH + h * DHEAD;
    const int irow = i0 + wv * 16 + l15;
    const short* qp = qt + hoff + (size_t)irow * CCH + quad * 8;
    const bf16x8 qa0 = *(const bf16x8*)qp;
    const bf16x8 qa1 = *(const bf16x8*)(qp + 32);

    // ---------------- Pass 1: denominators ----------------
    float denp[4] = {0.f, 0.f, 0.f, 0.f};
    for (int jt = 0; jt < 16; ++jt) {
        const int j0 = jt * 64;
        f32x4 s[4] = {{0,0,0,0},{0,0,0,0},{0,0,0,0},{0,0,0,0}};
#pragma unroll
        for (int ns = 0; ns < 4; ++ns) {
            const short* kp = kt + hoff + (size_t)(j0 + ns * 16 + l15) * CCH + quad * 8;
            bf16x8 k0 = *(const bf16x8*)kp;
            bf16x8 k1 = *(const bf16x8*)(kp + 32);
            s[ns] = MFMA16(qa0, k0, s[ns]);
            s[ns] = MFMA16(qa1, k1, s[ns]);
        }
#pragma unroll
        for (int ns = 0; ns < 4; ++ns)
#pragma unroll
            for (int r = 0; r < 4; ++r)
                denp[r] += __expf(s[ns][r] * SCALE);
    }
#pragma unroll
    for (int r = 0; r < 4; ++r) {
        denp[r] += __shfl_xor(denp[r], 1);
        denp[r] += __shfl_xor(denp[r], 2);
        denp[r] += __shfl_xor(denp[r], 4);
        denp[r] += __shfl_xor(denp[r], 8);
    }
    float rden[4];
#pragma unroll
    for (int r = 0; r < 4; ++r) rden[r] = 1.0f / denp[r];

    // ---------------- Pass 2: P, colsums, PV ----------------
    f32x4 oacc[4] = {{0,0,0,0},{0,0,0,0},{0,0,0,0},{0,0,0,0}};
    for (int jt = 0; jt < 16; ++jt) {
        const int j0 = jt * 64;
        f32x4 s[4] = {{0,0,0,0},{0,0,0,0},{0,0,0,0},{0,0,0,0}};
#pragma unroll
        for (int ns = 0; ns < 4; ++ns) {
            const short* kp = kt + hoff + (size_t)(j0 + ns * 16 + l15) * CCH + quad * 8;
            bf16x8 k0 = *(const bf16x8*)kp;
            bf16x8 k1 = *(const bf16x8*)(kp + 32);
            s[ns] = MFMA16(qa0, k0, s[ns]);
            s[ns] = MFMA16(qa1, k1, s[ns]);
        }
        float e[4][4];
#pragma unroll
        for (int ns = 0; ns < 4; ++ns)
#pragma unroll
            for (int r = 0; r < 4; ++r)
                e[ns][r] = __expf(s[ns][r] * SCALE);

        // column sums of normalized P (rows of this wave), 2 shfl per subtile
#pragma unroll
        for (int ns = 0; ns < 4; ++ns) {
            float cs = e[ns][0] * rden[0] + e[ns][1] * rden[1]
                     + e[ns][2] * rden[2] + e[ns][3] * rden[3];
            cs += __shfl_xor(cs, 16);
            cs += __shfl_xor(cs, 32);
            if (quad == 0) cmap[wv][j0 + ns * 16 + l15] += cs;
        }

        // P (unnormalized e) -> per-wave LDS strip in A-operand layout
#pragma unroll
        for (int ns = 0; ns < 4; ++ns)
#pragma unroll
            for (int r = 0; r < 4; ++r)
                Pst[wv][quad * 4 + r][ns * 16 + l15] = f2b(e[ns][r]);
        asm volatile("" ::: "memory");
        const short* pp = &Pst[wv][l15][quad * 8];
        bf16x8 pa0 = *(const bf16x8*)pp;
        bf16x8 pa1 = *(const bf16x8*)(pp + 32);
        asm volatile("" ::: "memory");

#pragma unroll
        for (int ds = 0; ds < 4; ++ds) {
            const short* vp = vc + ((size_t)(b * CCH + h * DHEAD + ds * 16 + l15)) * NTOK
                              + j0 + quad * 8;
            bf16x8 v0 = *(const bf16x8*)vp;
            bf16x8 v1 = *(const bf16x8*)(vp + 32);
            oacc[ds] = MFMA16(pa0, v0, oacc[ds]);
            oacc[ds] = MFMA16(pa1, v1, oacc[ds]);
        }
    }

    // store O (normalize rows by rden), token-major bf16
#pragma unroll
    for (int ds = 0; ds < 4; ++ds)
#pragma unroll
        for (int r = 0; r < 4; ++r) {
            const int i = i0 + wv * 16 + quad * 4 + r;
            omid[((size_t)(b * NTOK + i)) * CCH + h * DHEAD + ds * 16 + l15] =
                f2b(oacc[ds][r] * rden[r]);
        }

    __syncthreads();
    for (int idx = tid; idx < 1024; idx += 256) {
        const float s2 = cmap[0][idx] + cmap[1][idx] + cmap[2][idx] + cmap[3][idx];
        atomicAdd(amap + (size_t)b * NTOK + idx, s2 * (1.0f / (HEADS * NTOK)));
    }
}

// ---------------------------------------------------------------------------
extern "C" void kernel_launch(void* const* d_in, const int* in_sizes, int n_in,
                              void* d_out, int out_size, void* d_ws, size_t ws_size,
                              hipStream_t stream)
{
    const float* query   = (const float*)d_in[0];
    const float* context = (const float*)d_in[1];
    const float* Wq      = (const float*)d_in[2];
    const float* Wk      = (const float*)d_in[3];
    const float* Wv      = (const float*)d_in[4];
    const float* Wo      = (const float*)d_in[5];
    const float* bo      = (const float*)d_in[6];

    float* out = (float*)d_out;                          // [8,384,1024] fp32
    const size_t out_elems = (size_t)BATCH * CCH * NTOK;
    float* attn_map = out + out_elems;                   // [8,1024] fp32

    // workspace layout (bf16 = short)
    short* ws = (short*)d_ws;
    const size_t XT = (size_t)BATCH * NTOK * CCH;        // 3,145,728 elems
    const size_t WSZ = (size_t)CCH * CCH;                // 147,456 elems
    short* xtq  = ws;
    short* xtc  = xtq + XT;
    short* wqb  = xtc + XT;
    short* wkb  = wqb + WSZ;
    short* wvb  = wkb + WSZ;
    short* wob  = wvb + WSZ;
    short* qtb  = wob + WSZ;
    short* ktb  = qtb + XT;
    short* vcb  = ktb + XT;
    short* omid = vcb + XT;

    const dim3 blk(256);

    xpose_cvt<<<dim3(NTOK / 64, CCH / 64, BATCH), blk, 0, stream>>>(query, xtq);
    xpose_cvt<<<dim3(NTOK / 64, CCH / 64, BATCH), blk, 0, stream>>>(context, xtc);
    convert_w<<<dim3(144, 4), blk, 0, stream>>>(Wq, Wk, Wv, Wo, wqb, wkb, wvb, wob);

    gemm_tmaj<<<dim3(16, 6, BATCH), blk, 0, stream>>>(xtq, wqb, qtb);      // Q token-major
    gemm_tmaj<<<dim3(16, 6, BATCH), blk, 0, stream>>>(xtc, wkb, ktb);      // K token-major
    gemm_cmaj_bf16<<<dim3(16, 6, BATCH), blk, 0, stream>>>(wvb, xtc, vcb); // V channel-major

    hipMemsetAsync(attn_map, 0, (size_t)BATCH * NTOK * sizeof(float), stream);

    attn<<<dim3(16, BATCH * HEADS), blk, 0, stream>>>(qtb, ktb, vcb, omid, attn_map);

    gemm_cmaj_f32<<<dim3(16, 6, BATCH), blk, 0, stream>>>(wob, omid, bo, out);
}

// Round 3
// 224.540 us; speedup vs baseline: 2.3793x; 1.3907x over previous
//
#include <hip/hip_runtime.h>

// Problem constants
#define BATCH 8
#define CCH   384      // channels C == INNER
#define NTOK  1024     // H*W
#define HEADS 6
#define DHEAD 64
#define SCALE 0.125f   // 1/sqrt(64)

typedef __bf16 bf16x8 __attribute__((ext_vector_type(8)));
typedef float  f32x4  __attribute__((ext_vector_type(4)));

#define MFMA16(a, b, c) __builtin_amdgcn_mfma_f32_16x16x32_bf16((a), (b), (c), 0, 0, 0)

// fp32 -> bf16 RNE, as raw bits
__device__ __forceinline__ short f2b(float x) {
    unsigned u = __float_as_uint(x);
    u += 0x7fffu + ((u >> 16) & 1u);
    return (short)(u >> 16);
}

// async global->LDS, 16B per lane. LDS dst = wave-uniform base + lane*16.
__device__ __forceinline__ void gld_lds16(const short* gp, short* lp) {
    __builtin_amdgcn_global_load_lds(
        (const __attribute__((address_space(1))) void*)gp,
        (__attribute__((address_space(3))) void*)lp, 16, 0, 0);
}

// Stage a 64x64 bf16 tile (global rows of 64 elems, row stride gstride elems)
// into LDS (64 rows x 64 shorts) with XOR-swizzled 16B chunks:
// logical chunk c of row r lands at physical chunk c^(r&7).
// Wave wv stages rows [wv*16, wv*16+16). Two 1KB instructions per wave.
__device__ __forceinline__ void stage_tile(const short* gbase, size_t gstride,
                                           short* lbase, int wv, int lane) {
#pragma unroll
    for (int t = 0; t < 2; ++t) {
        const int row = t * 8 + (lane >> 3);           // row within 8-row group
        const int c   = (lane & 7) ^ (row & 7);        // logical chunk
        gld_lds16(gbase + (size_t)(wv * 16 + row) * gstride + c * 8,
                  lbase + (wv * 16 + t * 8) * 64);
    }
}

// Read a 16B A/B fragment chunk from a swizzled tile: row, logical chunk c.
__device__ __forceinline__ bf16x8 frag_read(const short* lbase, int row, int c) {
    const int pc = c ^ (row & 7);
    return *(const bf16x8*)(lbase + row * 64 + pc * 8);
}

// ---------------------------------------------------------------------------
// Transpose+convert: X[b][C][N] fp32 -> Xt[b][N][C] bf16
// ---------------------------------------------------------------------------
__global__ __launch_bounds__(256) void xpose_cvt(
    const float* __restrict__ X, short* __restrict__ Xt)
{
    __shared__ float tile[64][65];
    const int tid = threadIdx.x;
    const int b = blockIdx.z, n0 = blockIdx.x * 64, c0 = blockIdx.y * 64;
    const int tx = tid & 15, ty = tid >> 4;
#pragma unroll
    for (int rr = 0; rr < 4; ++rr) {
        const int c = rr * 16 + ty;
        float4 v = *(const float4*)&X[((size_t)(b * CCH + c0 + c)) * NTOK + n0 + tx * 4];
        tile[c][tx * 4 + 0] = v.x; tile[c][tx * 4 + 1] = v.y;
        tile[c][tx * 4 + 2] = v.z; tile[c][tx * 4 + 3] = v.w;
    }
    __syncthreads();
    const int n = tid >> 2, cb = (tid & 3) * 16;
    short tmp[16];
#pragma unroll
    for (int cc = 0; cc < 16; ++cc) tmp[cc] = f2b(tile[cb + cc][n]);
    short* dst = &Xt[((size_t)(b * NTOK + n0 + n)) * CCH + c0 + cb];
    *(int4*)dst = *(int4*)&tmp[0];
    *(int4*)(dst + 8) = *(int4*)&tmp[8];
}

// ---------------------------------------------------------------------------
// Convert 4 weight matrices fp32 -> bf16 (flat). grid (144, 4)
// ---------------------------------------------------------------------------
__global__ __launch_bounds__(256) void convert_w(
    const float* __restrict__ w0, const float* __restrict__ w1,
    const float* __restrict__ w2, const float* __restrict__ w3,
    short* __restrict__ o0, short* __restrict__ o1,
    short* __restrict__ o2, short* __restrict__ o3)
{
    const int idx = blockIdx.x * 256 + threadIdx.x;
    const int which = blockIdx.y;
    const float* s = which == 0 ? w0 : which == 1 ? w1 : which == 2 ? w2 : w3;
    short* d       = which == 0 ? o0 : which == 1 ? o1 : which == 2 ? o2 : o3;
    float4 v = ((const float4*)s)[idx];
    short4 o = make_short4(f2b(v.x), f2b(v.y), f2b(v.z), f2b(v.w));
    ((short4*)d)[idx] = o;
}

// ---------------------------------------------------------------------------
// GEMM, token-major out: Yt[b][tok][ch] = sum_k Xt[b][tok][k] * W[ch][k]
// 1D grid 768, swizzle: b = id%8 (XCD-local batch), 96 tiles per b.
// A-frags (Xt) all loaded upfront; B-frags (W) depth-2 ring prefetch.
// ---------------------------------------------------------------------------
__global__ __launch_bounds__(256) void gemm_tmaj(
    const short* __restrict__ Xt, const short* __restrict__ W,
    short* __restrict__ Yt)
{
    const int tid = threadIdx.x, l15 = tid & 15, quad = (tid >> 4) & 3, wv = tid >> 6;
    const int id = blockIdx.x;
    const int b = id & 7, rr = id >> 3;
    const int c0 = (rr % 6) * 64, t0 = (rr / 6) * 64;

    const short* arow = Xt + ((size_t)(b * NTOK + t0 + wv * 16 + l15)) * CCH + quad * 8;
    bf16x8 Af[12];
#pragma unroll
    for (int kc = 0; kc < 12; ++kc) Af[kc] = *(const bf16x8*)(arow + kc * 32);

    const short* wrow[4];
#pragma unroll
    for (int ns = 0; ns < 4; ++ns)
        wrow[ns] = W + ((size_t)(c0 + ns * 16 + l15)) * CCH + quad * 8;

    bf16x8 Bf[2][4];
#pragma unroll
    for (int ns = 0; ns < 4; ++ns) {
        Bf[0][ns] = *(const bf16x8*)(wrow[ns]);
        Bf[1][ns] = *(const bf16x8*)(wrow[ns] + 32);
    }

    f32x4 acc[4] = {{0,0,0,0},{0,0,0,0},{0,0,0,0},{0,0,0,0}};
#pragma unroll
    for (int kc = 0; kc < 12; ++kc) {
        const int cur = kc & 1;
        bf16x8 a = Af[kc];
        bf16x8 b0 = Bf[cur][0], b1 = Bf[cur][1], b2 = Bf[cur][2], b3 = Bf[cur][3];
        if (kc + 2 < 12) {
#pragma unroll
            for (int ns = 0; ns < 4; ++ns)
                Bf[cur][ns] = *(const bf16x8*)(wrow[ns] + (kc + 2) * 32);
        }
        acc[0] = MFMA16(a, b0, acc[0]);
        acc[1] = MFMA16(a, b1, acc[1]);
        acc[2] = MFMA16(a, b2, acc[2]);
        acc[3] = MFMA16(a, b3, acc[3]);
    }
#pragma unroll
    for (int ns = 0; ns < 4; ++ns)
#pragma unroll
        for (int r = 0; r < 4; ++r) {
            const int tok = t0 + wv * 16 + quad * 4 + r;
            Yt[((size_t)(b * NTOK + tok)) * CCH + c0 + ns * 16 + l15] = f2b(acc[ns][r]);
        }
}

// ---------------------------------------------------------------------------
// GEMM, channel-major bf16 out: Y[b][ch][tok] = sum_k W[ch][k]*Xt[b][tok][k]
// ---------------------------------------------------------------------------
__global__ __launch_bounds__(256) void gemm_cmaj_bf16(
    const short* __restrict__ W, const short* __restrict__ Xt,
    short* __restrict__ Y)
{
    const int tid = threadIdx.x, l15 = tid & 15, quad = (tid >> 4) & 3, wv = tid >> 6;
    const int id = blockIdx.x;
    const int b = id & 7, rr = id >> 3;
    const int m0 = (rr % 6) * 64, n0 = (rr / 6) * 64;

    const short* arow = W + ((size_t)(m0 + wv * 16 + l15)) * CCH + quad * 8;
    bf16x8 Af[12];
#pragma unroll
    for (int kc = 0; kc < 12; ++kc) Af[kc] = *(const bf16x8*)(arow + kc * 32);

    const short* xrow[4];
#pragma unroll
    for (int ns = 0; ns < 4; ++ns)
        xrow[ns] = Xt + ((size_t)(b * NTOK + n0 + ns * 16 + l15)) * CCH + quad * 8;

    bf16x8 Bf[2][4];
#pragma unroll
    for (int ns = 0; ns < 4; ++ns) {
        Bf[0][ns] = *(const bf16x8*)(xrow[ns]);
        Bf[1][ns] = *(const bf16x8*)(xrow[ns] + 32);
    }

    f32x4 acc[4] = {{0,0,0,0},{0,0,0,0},{0,0,0,0},{0,0,0,0}};
#pragma unroll
    for (int kc = 0; kc < 12; ++kc) {
        const int cur = kc & 1;
        bf16x8 a = Af[kc];
        bf16x8 b0 = Bf[cur][0], b1 = Bf[cur][1], b2 = Bf[cur][2], b3 = Bf[cur][3];
        if (kc + 2 < 12) {
#pragma unroll
            for (int ns = 0; ns < 4; ++ns)
                Bf[cur][ns] = *(const bf16x8*)(xrow[ns] + (kc + 2) * 32);
        }
        acc[0] = MFMA16(a, b0, acc[0]);
        acc[1] = MFMA16(a, b1, acc[1]);
        acc[2] = MFMA16(a, b2, acc[2]);
        acc[3] = MFMA16(a, b3, acc[3]);
    }
#pragma unroll
    for (int ns = 0; ns < 4; ++ns)
#pragma unroll
        for (int r = 0; r < 4; ++r) {
            const int ch = m0 + wv * 16 + quad * 4 + r;
            Y[((size_t)(b * CCH + ch)) * NTOK + n0 + ns * 16 + l15] = f2b(acc[ns][r]);
        }
}

// ---------------------------------------------------------------------------
// GEMM, channel-major fp32 out + bias (final projection)
// ---------------------------------------------------------------------------
__global__ __launch_bounds__(256) void gemm_cmaj_f32(
    const short* __restrict__ W, const short* __restrict__ Xt,
    const float* __restrict__ bias, float* __restrict__ Y)
{
    const int tid = threadIdx.x, l15 = tid & 15, quad = (tid >> 4) & 3, wv = tid >> 6;
    const int id = blockIdx.x;
    const int b = id & 7, rr = id >> 3;
    const int m0 = (rr % 6) * 64, n0 = (rr / 6) * 64;

    const short* arow = W + ((size_t)(m0 + wv * 16 + l15)) * CCH + quad * 8;
    bf16x8 Af[12];
#pragma unroll
    for (int kc = 0; kc < 12; ++kc) Af[kc] = *(const bf16x8*)(arow + kc * 32);

    const short* xrow[4];
#pragma unroll
    for (int ns = 0; ns < 4; ++ns)
        xrow[ns] = Xt + ((size_t)(b * NTOK + n0 + ns * 16 + l15)) * CCH + quad * 8;

    bf16x8 Bf[2][4];
#pragma unroll
    for (int ns = 0; ns < 4; ++ns) {
        Bf[0][ns] = *(const bf16x8*)(xrow[ns]);
        Bf[1][ns] = *(const bf16x8*)(xrow[ns] + 32);
    }

    f32x4 acc[4] = {{0,0,0,0},{0,0,0,0},{0,0,0,0},{0,0,0,0}};
#pragma unroll
    for (int kc = 0; kc < 12; ++kc) {
        const int cur = kc & 1;
        bf16x8 a = Af[kc];
        bf16x8 b0 = Bf[cur][0], b1 = Bf[cur][1], b2 = Bf[cur][2], b3 = Bf[cur][3];
        if (kc + 2 < 12) {
#pragma unroll
            for (int ns = 0; ns < 4; ++ns)
                Bf[cur][ns] = *(const bf16x8*)(xrow[ns] + (kc + 2) * 32);
        }
        acc[0] = MFMA16(a, b0, acc[0]);
        acc[1] = MFMA16(a, b1, acc[1]);
        acc[2] = MFMA16(a, b2, acc[2]);
        acc[3] = MFMA16(a, b3, acc[3]);
    }
#pragma unroll
    for (int ns = 0; ns < 4; ++ns)
#pragma unroll
        for (int r = 0; r < 4; ++r) {
            const int ch = m0 + wv * 16 + quad * 4 + r;
            Y[((size_t)(b * CCH + ch)) * NTOK + n0 + ns * 16 + l15] = acc[ns][r] + bias[ch];
        }
}

// ---------------------------------------------------------------------------
// Fused attention, MFMA + LDS-staged K/V (double-buffered, async).
// 1D grid 768: xcd=id%8 -> b=xcd (L2 locality); r=id/8: h=r%6, i0=(r/6)*64.
// Pass 1: den_i = sum_j exp(S_ij*scale) (no max-sub: |logit| <~ 1)
// Pass 2: restage K + V; P normalized at Pst write; PV MFMA; colsum via shfl
//         + colbuf double-buffer reduced after each staging barrier.
// ---------------------------------------------------------------------------
__global__ __launch_bounds__(256) void attn(
    const short* __restrict__ qt, const short* __restrict__ kt,
    const short* __restrict__ vc, short* __restrict__ omid,
    float* __restrict__ amap)
{
    __shared__ __align__(16) short Kst[2][64 * 64];   // 16 KB
    __shared__ __align__(16) short Vst[2][64 * 64];   // 16 KB
    __shared__ __align__(16) short Pst[4][16][72];    // 9.2 KB
    __shared__ float colbuf[2][4][64];                // 2 KB

    const int tid = threadIdx.x, lane = tid & 63;
    const int l15 = tid & 15, quad = (tid >> 4) & 3, wv = tid >> 6;
    const int id = blockIdx.x;
    const int b = id & 7, rr = id >> 3;
    const int h = rr % 6, i0 = (rr / 6) * 64;

    const size_t hoff = (size_t)b * NTOK * CCH + h * DHEAD;
    const short* Kg = kt + hoff;                                   // stride CCH
    const short* Vg = vc + ((size_t)(b * CCH + h * DHEAD)) * NTOK; // stride NTOK

    // Q frags (registers, used by every jt)
    const short* qp = qt + hoff + (size_t)(i0 + wv * 16 + l15) * CCH + quad * 8;
    const bf16x8 qa0 = *(const bf16x8*)qp;
    const bf16x8 qa1 = *(const bf16x8*)(qp + 32);

    // ---------------- Pass 1: denominators ----------------
    stage_tile(Kg, CCH, Kst[0], wv, lane);
    __syncthreads();

    float den[4] = {0.f, 0.f, 0.f, 0.f};
    for (int jt = 0; jt < 16; ++jt) {
        const int cur = jt & 1;
        if (jt < 15)
            stage_tile(Kg + (size_t)(jt + 1) * 64 * CCH, CCH, Kst[cur ^ 1], wv, lane);
        f32x4 s[4] = {{0,0,0,0},{0,0,0,0},{0,0,0,0},{0,0,0,0}};
#pragma unroll
        for (int ns = 0; ns < 4; ++ns) {
            const int row = ns * 16 + l15;
            bf16x8 k0 = frag_read(Kst[cur], row, quad);
            bf16x8 k1 = frag_read(Kst[cur], row, quad + 4);
            s[ns] = MFMA16(qa0, k0, s[ns]);
            s[ns] = MFMA16(qa1, k1, s[ns]);
        }
#pragma unroll
        for (int ns = 0; ns < 4; ++ns)
#pragma unroll
            for (int r = 0; r < 4; ++r)
                den[r] += __expf(s[ns][r] * SCALE);
        __syncthreads();
    }
#pragma unroll
    for (int r = 0; r < 4; ++r) {
        den[r] += __shfl_xor(den[r], 1);
        den[r] += __shfl_xor(den[r], 2);
        den[r] += __shfl_xor(den[r], 4);
        den[r] += __shfl_xor(den[r], 8);
    }
    float rden[4];
#pragma unroll
    for (int r = 0; r < 4; ++r) rden[r] = 1.0f / den[r];

    // ---------------- Pass 2: P, PV, colsums ----------------
    stage_tile(Kg, CCH, Kst[0], wv, lane);
    stage_tile(Vg, NTOK, Vst[0], wv, lane);
    __syncthreads();

    f32x4 oacc[4] = {{0,0,0,0},{0,0,0,0},{0,0,0,0},{0,0,0,0}};
    for (int jt = 0; jt < 16; ++jt) {
        const int cur = jt & 1;
        if (jt < 15) {
            stage_tile(Kg + (size_t)(jt + 1) * 64 * CCH, CCH, Kst[cur ^ 1], wv, lane);
            stage_tile(Vg + (size_t)(jt + 1) * 64, NTOK, Vst[cur ^ 1], wv, lane);
        }
        f32x4 s[4] = {{0,0,0,0},{0,0,0,0},{0,0,0,0},{0,0,0,0}};
#pragma unroll
        for (int ns = 0; ns < 4; ++ns) {
            const int row = ns * 16 + l15;
            bf16x8 k0 = frag_read(Kst[cur], row, quad);
            bf16x8 k1 = frag_read(Kst[cur], row, quad + 4);
            s[ns] = MFMA16(qa0, k0, s[ns]);
            s[ns] = MFMA16(qa1, k1, s[ns]);
        }
        // normalized P
        float p[4][4];
#pragma unroll
        for (int ns = 0; ns < 4; ++ns)
#pragma unroll
            for (int r = 0; r < 4; ++r)
                p[ns][r] = __expf(s[ns][r] * SCALE) * rden[r];

        // column sums over this wave's 16 i-rows
#pragma unroll
        for (int ns = 0; ns < 4; ++ns) {
            float cs = p[ns][0] + p[ns][1] + p[ns][2] + p[ns][3];
            cs += __shfl_xor(cs, 16);
            cs += __shfl_xor(cs, 32);
            if (quad == 0) colbuf[cur][wv][ns * 16 + l15] = cs;
        }

        // P -> per-wave LDS strip in A-operand layout (wave-internal)
#pragma unroll
        for (int ns = 0; ns < 4; ++ns)
#pragma unroll
            for (int r = 0; r < 4; ++r)
                Pst[wv][quad * 4 + r][ns * 16 + l15] = f2b(p[ns][r]);
        asm volatile("" ::: "memory");
        const short* pp = &Pst[wv][l15][quad * 8];
        bf16x8 pa0 = *(const bf16x8*)pp;
        bf16x8 pa1 = *(const bf16x8*)(pp + 32);
        asm volatile("" ::: "memory");

#pragma unroll
        for (int ds = 0; ds < 4; ++ds) {
            const int row = ds * 16 + l15;
            bf16x8 v0 = frag_read(Vst[cur], row, quad);
            bf16x8 v1 = frag_read(Vst[cur], row, quad + 4);
            oacc[ds] = MFMA16(pa0, v0, oacc[ds]);
            oacc[ds] = MFMA16(pa1, v1, oacc[ds]);
        }
        __syncthreads();
        // reduce this jt's colsums (colbuf[cur] stable until jt+2)
        if (tid < 64) {
            const float t = colbuf[cur][0][tid] + colbuf[cur][1][tid]
                          + colbuf[cur][2][tid] + colbuf[cur][3][tid];
            atomicAdd(amap + (size_t)b * NTOK + jt * 64 + tid,
                      t * (1.0f / (HEADS * NTOK)));
        }
    }

    // store O (already normalized), token-major bf16
#pragma unroll
    for (int ds = 0; ds < 4; ++ds)
#pragma unroll
        for (int r = 0; r < 4; ++r) {
            const int i = i0 + wv * 16 + quad * 4 + r;
            omid[((size_t)(b * NTOK + i)) * CCH + h * DHEAD + ds * 16 + l15] =
                f2b(oacc[ds][r]);
        }
}

// ---------------------------------------------------------------------------
extern "C" void kernel_launch(void* const* d_in, const int* in_sizes, int n_in,
                              void* d_out, int out_size, void* d_ws, size_t ws_size,
                              hipStream_t stream)
{
    const float* query   = (const float*)d_in[0];
    const float* context = (const float*)d_in[1];
    const float* Wq      = (const float*)d_in[2];
    const float* Wk      = (const float*)d_in[3];
    const float* Wv      = (const float*)d_in[4];
    const float* Wo      = (const float*)d_in[5];
    const float* bo      = (const float*)d_in[6];

    float* out = (float*)d_out;                          // [8,384,1024] fp32
    const size_t out_elems = (size_t)BATCH * CCH * NTOK;
    float* attn_map = out + out_elems;                   // [8,1024] fp32

    short* ws = (short*)d_ws;
    const size_t XT = (size_t)BATCH * NTOK * CCH;
    const size_t WSZ = (size_t)CCH * CCH;
    short* xtq  = ws;
    short* xtc  = xtq + XT;
    short* wqb  = xtc + XT;
    short* wkb  = wqb + WSZ;
    short* wvb  = wkb + WSZ;
    short* wob  = wvb + WSZ;
    short* qtb  = wob + WSZ;
    short* ktb  = qtb + XT;
    short* vcb  = ktb + XT;
    short* omid = vcb + XT;

    const dim3 blk(256);

    xpose_cvt<<<dim3(NTOK / 64, CCH / 64, BATCH), blk, 0, stream>>>(query, xtq);
    xpose_cvt<<<dim3(NTOK / 64, CCH / 64, BATCH), blk, 0, stream>>>(context, xtc);
    convert_w<<<dim3(144, 4), blk, 0, stream>>>(Wq, Wk, Wv, Wo, wqb, wkb, wvb, wob);

    gemm_tmaj<<<dim3(768), blk, 0, stream>>>(xtq, wqb, qtb);      // Q token-major
    gemm_tmaj<<<dim3(768), blk, 0, stream>>>(xtc, wkb, ktb);      // K token-major
    gemm_cmaj_bf16<<<dim3(768), blk, 0, stream>>>(wvb, xtc, vcb); // V channel-major

    hipMemsetAsync(attn_map, 0, (size_t)BATCH * NTOK * sizeof(float), stream);

    attn<<<dim3(768), blk, 0, stream>>>(qtb, ktb, vcb, omid, attn_map);

    gemm_cmaj_f32<<<dim3(768), blk, 0, stream>>>(wob, omid, bo, out);
}

// Round 4
// 167.875 us; speedup vs baseline: 3.1824x; 1.3375x over previous
//
#include <hip/hip_runtime.h>

// Problem constants
#define BATCH 8
#define CCH   384      // channels C == INNER
#define NTOK  1024     // H*W
#define HEADS 6
#define DHEAD 64
#define SCALE 0.125f   // 1/sqrt(64)

typedef __bf16 bf16x8 __attribute__((ext_vector_type(8)));
typedef float  f32x4  __attribute__((ext_vector_type(4)));

#define MFMA16(a, b, c) __builtin_amdgcn_mfma_f32_16x16x32_bf16((a), (b), (c), 0, 0, 0)

// fp32 -> bf16 RNE, as raw bits
__device__ __forceinline__ short f2b(float x) {
    unsigned u = __float_as_uint(x);
    u += 0x7fffu + ((u >> 16) & 1u);
    return (short)(u >> 16);
}

// async global->LDS, 16B per lane. LDS dst = wave-uniform base + lane*16.
__device__ __forceinline__ void gld_lds16(const short* gp, short* lp) {
    __builtin_amdgcn_global_load_lds(
        (const __attribute__((address_space(1))) void*)gp,
        (__attribute__((address_space(3))) void*)lp, 16, 0, 0);
}

// Stage a 64x64 bf16 tile (64 rows, row stride gstride elems) into LDS
// (64 rows x 64 shorts) with XOR-swizzled 16B chunks: logical chunk c of
// row r lands at physical chunk c^(r&7). Wave wv stages rows [wv*16,+16).
__device__ __forceinline__ void stage_tile(const short* gbase, size_t gstride,
                                           short* lbase, int wv, int lane) {
#pragma unroll
    for (int t = 0; t < 2; ++t) {
        const int row = t * 8 + (lane >> 3);
        const int c   = (lane & 7) ^ (row & 7);
        gld_lds16(gbase + (size_t)(wv * 16 + row) * gstride + c * 8,
                  lbase + (wv * 16 + t * 8) * 64);
    }
}

// Read a 16B fragment chunk from a swizzled tile: row, logical chunk c (0..7).
__device__ __forceinline__ bf16x8 frag_read(const short* lbase, int row, int c) {
    const int pc = c ^ (row & 7);
    return *(const bf16x8*)(lbase + row * 64 + pc * 8);
}

// ---------------------------------------------------------------------------
// Transpose+convert both inputs: X[b][C][N] fp32 -> Xt[b][N][C] bf16
// grid (16, 6, 16): z<8 -> query->xtq, z>=8 -> context->xtc
// ---------------------------------------------------------------------------
__global__ __launch_bounds__(256) void xpose_both(
    const float* __restrict__ Xq, const float* __restrict__ Xc,
    short* __restrict__ Xtq, short* __restrict__ Xtc)
{
    __shared__ float tile[64][65];
    const int tid = threadIdx.x;
    const int zz = blockIdx.z;
    const float* X = (zz < 8) ? Xq : Xc;
    short* Xt      = (zz < 8) ? Xtq : Xtc;
    const int b = zz & 7, n0 = blockIdx.x * 64, c0 = blockIdx.y * 64;
    const int tx = tid & 15, ty = tid >> 4;
#pragma unroll
    for (int rr = 0; rr < 4; ++rr) {
        const int c = rr * 16 + ty;
        float4 v = *(const float4*)&X[((size_t)(b * CCH + c0 + c)) * NTOK + n0 + tx * 4];
        tile[c][tx * 4 + 0] = v.x; tile[c][tx * 4 + 1] = v.y;
        tile[c][tx * 4 + 2] = v.z; tile[c][tx * 4 + 3] = v.w;
    }
    __syncthreads();
    const int n = tid >> 2, cb = (tid & 3) * 16;
    short tmp[16];
#pragma unroll
    for (int cc = 0; cc < 16; ++cc) tmp[cc] = f2b(tile[cb + cc][n]);
    short* dst = &Xt[((size_t)(b * NTOK + n0 + n)) * CCH + c0 + cb];
    *(int4*)dst = *(int4*)&tmp[0];
    *(int4*)(dst + 8) = *(int4*)&tmp[8];
}

// ---------------------------------------------------------------------------
// Convert 4 weight matrices fp32 -> bf16 (flat). grid (144, 4)
// ---------------------------------------------------------------------------
__global__ __launch_bounds__(256) void convert_w(
    const float* __restrict__ w0, const float* __restrict__ w1,
    const float* __restrict__ w2, const float* __restrict__ w3,
    short* __restrict__ o0, short* __restrict__ o1,
    short* __restrict__ o2, short* __restrict__ o3)
{
    const int idx = blockIdx.x * 256 + threadIdx.x;
    const int which = blockIdx.y;
    const float* s = which == 0 ? w0 : which == 1 ? w1 : which == 2 ? w2 : w3;
    short* d       = which == 0 ? o0 : which == 1 ? o1 : which == 2 ? o2 : o3;
    float4 v = ((const float4*)s)[idx];
    short4 o = make_short4(f2b(v.x), f2b(v.y), f2b(v.z), f2b(v.w));
    ((short4*)d)[idx] = o;
}

// ---------------------------------------------------------------------------
// Fused QKV projection. 2304 blocks: b=id%8 (XCD-local), q=id/8 (0..287):
// which=q%3 (0:Q tmaj, 1:K tmaj, 2:V cmaj), rr=q/3: c0=(rr%6)*64, t0=(rr/6)*64.
// B-operand panel (64 rows x 384 k) staged in LDS (xor-swizzled, 48 KB);
// A-operand frags (12) direct-from-global upfront, hidden behind staging.
// tmaj: A=X tokens, B=W ch rows, out Yt[tok][ch]
// cmaj: A=W ch rows, B=X tokens, out Y[ch][tok]
// ---------------------------------------------------------------------------
__global__ __launch_bounds__(256) void proj_qkv(
    const short* __restrict__ xtq, const short* __restrict__ xtc,
    const short* __restrict__ wq, const short* __restrict__ wk,
    const short* __restrict__ wv,
    short* __restrict__ qout, short* __restrict__ kout, short* __restrict__ vout)
{
    __shared__ __align__(16) short Bst[6][64 * 64];   // 48 KB
    const int tid = threadIdx.x, lane = tid & 63;
    const int l15 = tid & 15, quad = (tid >> 4) & 3, wv4 = tid >> 6;
    const int id = blockIdx.x;
    const int b = id & 7, q = id >> 3;
    const int which = q % 3, rr = q / 3;
    const int c0 = (rr % 6) * 64, t0 = (rr / 6) * 64;

    const short* xa   = (which == 0) ? xtq : xtc;
    const short* Wsel = (which == 0) ? wq : (which == 1) ? wk : wv;

    const short* Abase, *Bbase;
    if (which < 2) {
        Abase = xa + ((size_t)(b * NTOK + t0)) * CCH;
        Bbase = Wsel + (size_t)c0 * CCH;
    } else {
        Abase = Wsel + (size_t)c0 * CCH;
        Bbase = xa + ((size_t)(b * NTOK + t0)) * CCH;
    }

    // A-frags upfront (48 VGPR), then staging; both drain at the barrier
    const short* arow = Abase + (size_t)(wv4 * 16 + l15) * CCH + quad * 8;
    bf16x8 Af[12];
#pragma unroll
    for (int kc = 0; kc < 12; ++kc) Af[kc] = *(const bf16x8*)(arow + kc * 32);
#pragma unroll
    for (int kt = 0; kt < 6; ++kt)
        stage_tile(Bbase + kt * 64, CCH, &Bst[kt][0], wv4, lane);
    __syncthreads();

    f32x4 acc[4] = {{0,0,0,0},{0,0,0,0},{0,0,0,0},{0,0,0,0}};
#pragma unroll
    for (int kc = 0; kc < 12; ++kc) {
        bf16x8 a = Af[kc];
#pragma unroll
        for (int ns = 0; ns < 4; ++ns) {
            bf16x8 bb = frag_read(&Bst[kc >> 1][0], ns * 16 + l15,
                                  ((kc & 1) << 2) | quad);
            acc[ns] = MFMA16(a, bb, acc[ns]);
        }
    }

    if (which < 2) {
        short* out = (which == 0) ? qout : kout;
#pragma unroll
        for (int ns = 0; ns < 4; ++ns)
#pragma unroll
            for (int r = 0; r < 4; ++r) {
                const int tok = t0 + wv4 * 16 + quad * 4 + r;
                out[((size_t)(b * NTOK + tok)) * CCH + c0 + ns * 16 + l15] =
                    f2b(acc[ns][r]);
            }
    } else {
#pragma unroll
        for (int ns = 0; ns < 4; ++ns)
#pragma unroll
            for (int r = 0; r < 4; ++r) {
                const int ch = c0 + wv4 * 16 + quad * 4 + r;
                vout[((size_t)(b * CCH + ch)) * NTOK + t0 + ns * 16 + l15] =
                    f2b(acc[ns][r]);
            }
    }
}

// ---------------------------------------------------------------------------
// Output projection: out[b][ch][tok] = sum_k Wo[ch][k]*omid[b][tok][k] + bo[ch]
// Same structure: stage omid token-panel, direct-load Wo rows. fp32 out.
// ---------------------------------------------------------------------------
__global__ __launch_bounds__(256) void o_proj(
    const short* __restrict__ wo, const short* __restrict__ omid,
    const float* __restrict__ bias, float* __restrict__ Y)
{
    __shared__ __align__(16) short Bst[6][64 * 64];
    const int tid = threadIdx.x, lane = tid & 63;
    const int l15 = tid & 15, quad = (tid >> 4) & 3, wv4 = tid >> 6;
    const int id = blockIdx.x;
    const int b = id & 7, rr = id >> 3;
    const int m0 = (rr % 6) * 64, n0 = (rr / 6) * 64;

    const short* Abase = wo + (size_t)m0 * CCH;
    const short* Bbase = omid + ((size_t)(b * NTOK + n0)) * CCH;

    const short* arow = Abase + (size_t)(wv4 * 16 + l15) * CCH + quad * 8;
    bf16x8 Af[12];
#pragma unroll
    for (int kc = 0; kc < 12; ++kc) Af[kc] = *(const bf16x8*)(arow + kc * 32);
#pragma unroll
    for (int kt = 0; kt < 6; ++kt)
        stage_tile(Bbase + kt * 64, CCH, &Bst[kt][0], wv4, lane);
    __syncthreads();

    f32x4 acc[4] = {{0,0,0,0},{0,0,0,0},{0,0,0,0},{0,0,0,0}};
#pragma unroll
    for (int kc = 0; kc < 12; ++kc) {
        bf16x8 a = Af[kc];
#pragma unroll
        for (int ns = 0; ns < 4; ++ns) {
            bf16x8 bb = frag_read(&Bst[kc >> 1][0], ns * 16 + l15,
                                  ((kc & 1) << 2) | quad);
            acc[ns] = MFMA16(a, bb, acc[ns]);
        }
    }
#pragma unroll
    for (int ns = 0; ns < 4; ++ns)
#pragma unroll
        for (int r = 0; r < 4; ++r) {
            const int ch = m0 + wv4 * 16 + quad * 4 + r;
            Y[((size_t)(b * CCH + ch)) * NTOK + n0 + ns * 16 + l15] =
                acc[ns][r] + bias[ch];
        }
}

// ---------------------------------------------------------------------------
// Fused attention, MFMA + LDS-staged K/V (double-buffered, async).
// 768 blocks: b=id%8 (XCD-local); rr=id/8: h=rr%6, i0=(rr/6)*64.
// Pass 1: den_i = sum_j exp(S_ij*scale) (no max-sub: |logit| <~ 1)
// Pass 2: restage K+V; P normalized at Pst write (xor-swizzled chunks:
// writes 2-way (free), reads 16B-aligned conflict-free); PV MFMA; colsum
// via shfl + colbuf double-buffer reduced after each staging barrier.
// ---------------------------------------------------------------------------
__global__ __launch_bounds__(256) void attn(
    const short* __restrict__ qt, const short* __restrict__ kt,
    const short* __restrict__ vc, short* __restrict__ omid,
    float* __restrict__ amap)
{
    __shared__ __align__(16) short Kst[2][64 * 64];   // 16 KB
    __shared__ __align__(16) short Vst[2][64 * 64];   // 16 KB
    __shared__ __align__(16) short Pst[4][16][64];    // 8 KB, chunk-xor swizzled
    __shared__ float colbuf[2][4][64];                // 2 KB

    const int tid = threadIdx.x, lane = tid & 63;
    const int l15 = tid & 15, quad = (tid >> 4) & 3, wv = tid >> 6;
    const int id = blockIdx.x;
    const int b = id & 7, rr = id >> 3;
    const int h = rr % 6, i0 = (rr / 6) * 64;

    const size_t hoff = (size_t)b * NTOK * CCH + h * DHEAD;
    const short* Kg = kt + hoff;                                   // stride CCH
    const short* Vg = vc + ((size_t)(b * CCH + h * DHEAD)) * NTOK; // stride NTOK

    const short* qp = qt + hoff + (size_t)(i0 + wv * 16 + l15) * CCH + quad * 8;
    const bf16x8 qa0 = *(const bf16x8*)qp;
    const bf16x8 qa1 = *(const bf16x8*)(qp + 32);

    // ---------------- Pass 1: denominators ----------------
    stage_tile(Kg, CCH, Kst[0], wv, lane);
    __syncthreads();

    float den[4] = {0.f, 0.f, 0.f, 0.f};
    for (int jt = 0; jt < 16; ++jt) {
        const int cur = jt & 1;
        if (jt < 15)
            stage_tile(Kg + (size_t)(jt + 1) * 64 * CCH, CCH, Kst[cur ^ 1], wv, lane);
        f32x4 s[4] = {{0,0,0,0},{0,0,0,0},{0,0,0,0},{0,0,0,0}};
#pragma unroll
        for (int ns = 0; ns < 4; ++ns) {
            const int row = ns * 16 + l15;
            bf16x8 k0 = frag_read(Kst[cur], row, quad);
            bf16x8 k1 = frag_read(Kst[cur], row, quad + 4);
            s[ns] = MFMA16(qa0, k0, s[ns]);
            s[ns] = MFMA16(qa1, k1, s[ns]);
        }
#pragma unroll
        for (int ns = 0; ns < 4; ++ns)
#pragma unroll
            for (int r = 0; r < 4; ++r)
                den[r] += __expf(s[ns][r] * SCALE);
        __syncthreads();
    }
#pragma unroll
    for (int r = 0; r < 4; ++r) {
        den[r] += __shfl_xor(den[r], 1);
        den[r] += __shfl_xor(den[r], 2);
        den[r] += __shfl_xor(den[r], 4);
        den[r] += __shfl_xor(den[r], 8);
    }
    float rden[4];
#pragma unroll
    for (int r = 0; r < 4; ++r) rden[r] = 1.0f / den[r];

    // ---------------- Pass 2: P, PV, colsums ----------------
    stage_tile(Kg, CCH, Kst[0], wv, lane);
    stage_tile(Vg, NTOK, Vst[0], wv, lane);
    __syncthreads();

    f32x4 oacc[4] = {{0,0,0,0},{0,0,0,0},{0,0,0,0},{0,0,0,0}};
    for (int jt = 0; jt < 16; ++jt) {
        const int cur = jt & 1;
        if (jt < 15) {
            stage_tile(Kg + (size_t)(jt + 1) * 64 * CCH, CCH, Kst[cur ^ 1], wv, lane);
            stage_tile(Vg + (size_t)(jt + 1) * 64, NTOK, Vst[cur ^ 1], wv, lane);
        }
        f32x4 s[4] = {{0,0,0,0},{0,0,0,0},{0,0,0,0},{0,0,0,0}};
#pragma unroll
        for (int ns = 0; ns < 4; ++ns) {
            const int row = ns * 16 + l15;
            bf16x8 k0 = frag_read(Kst[cur], row, quad);
            bf16x8 k1 = frag_read(Kst[cur], row, quad + 4);
            s[ns] = MFMA16(qa0, k0, s[ns]);
            s[ns] = MFMA16(qa1, k1, s[ns]);
        }
        float p[4][4];
#pragma unroll
        for (int ns = 0; ns < 4; ++ns)
#pragma unroll
            for (int r = 0; r < 4; ++r)
                p[ns][r] = __expf(s[ns][r] * SCALE) * rden[r];

        // column sums over this wave's 16 i-rows
#pragma unroll
        for (int ns = 0; ns < 4; ++ns) {
            float cs = p[ns][0] + p[ns][1] + p[ns][2] + p[ns][3];
            cs += __shfl_xor(cs, 16);
            cs += __shfl_xor(cs, 32);
            if (quad == 0) colbuf[cur][wv][ns * 16 + l15] = cs;
        }

        // P -> per-wave swizzled LDS strip (A-operand layout for PV)
#pragma unroll
        for (int ns = 0; ns < 4; ++ns) {
            const int c = ns * 2 + (l15 >> 3);      // logical 16B chunk of col
#pragma unroll
            for (int r = 0; r < 4; ++r) {
                const int row = quad * 4 + r;
                Pst[wv][row][((c ^ (row & 7)) << 3) | (l15 & 7)] = f2b(p[ns][r]);
            }
        }
        asm volatile("" ::: "memory");
        const int pc0 = quad ^ (l15 & 7);
        const int pc1 = (quad + 4) ^ (l15 & 7);
        bf16x8 pa0 = *(const bf16x8*)&Pst[wv][l15][pc0 * 8];
        bf16x8 pa1 = *(const bf16x8*)&Pst[wv][l15][pc1 * 8];
        asm volatile("" ::: "memory");

#pragma unroll
        for (int ds = 0; ds < 4; ++ds) {
            const int row = ds * 16 + l15;
            bf16x8 v0 = frag_read(Vst[cur], row, quad);
            bf16x8 v1 = frag_read(Vst[cur], row, quad + 4);
            oacc[ds] = MFMA16(pa0, v0, oacc[ds]);
            oacc[ds] = MFMA16(pa1, v1, oacc[ds]);
        }
        __syncthreads();
        if (tid < 64) {
            const float t = colbuf[cur][0][tid] + colbuf[cur][1][tid]
                          + colbuf[cur][2][tid] + colbuf[cur][3][tid];
            atomicAdd(amap + (size_t)b * NTOK + jt * 64 + tid,
                      t * (1.0f / (HEADS * NTOK)));
        }
    }

    // store O (already normalized), token-major bf16
#pragma unroll
    for (int ds = 0; ds < 4; ++ds)
#pragma unroll
        for (int r = 0; r < 4; ++r) {
            const int i = i0 + wv * 16 + quad * 4 + r;
            omid[((size_t)(b * NTOK + i)) * CCH + h * DHEAD + ds * 16 + l15] =
                f2b(oacc[ds][r]);
        }
}

// ---------------------------------------------------------------------------
extern "C" void kernel_launch(void* const* d_in, const int* in_sizes, int n_in,
                              void* d_out, int out_size, void* d_ws, size_t ws_size,
                              hipStream_t stream)
{
    const float* query   = (const float*)d_in[0];
    const float* context = (const float*)d_in[1];
    const float* Wq      = (const float*)d_in[2];
    const float* Wk      = (const float*)d_in[3];
    const float* Wv      = (const float*)d_in[4];
    const float* Wo      = (const float*)d_in[5];
    const float* bo      = (const float*)d_in[6];

    float* out = (float*)d_out;                          // [8,384,1024] fp32
    const size_t out_elems = (size_t)BATCH * CCH * NTOK;
    float* attn_map = out + out_elems;                   // [8,1024] fp32

    short* ws = (short*)d_ws;
    const size_t XT = (size_t)BATCH * NTOK * CCH;
    const size_t WSZ = (size_t)CCH * CCH;
    short* xtq  = ws;
    short* xtc  = xtq + XT;
    short* wqb  = xtc + XT;
    short* wkb  = wqb + WSZ;
    short* wvb  = wkb + WSZ;
    short* wob  = wvb + WSZ;
    short* qtb  = wob + WSZ;
    short* ktb  = qtb + XT;
    short* vcb  = ktb + XT;
    short* omid = vcb + XT;

    const dim3 blk(256);

    xpose_both<<<dim3(16, 6, 16), blk, 0, stream>>>(query, context, xtq, xtc);
    convert_w<<<dim3(144, 4), blk, 0, stream>>>(Wq, Wk, Wv, Wo, wqb, wkb, wvb, wob);

    proj_qkv<<<dim3(2304), blk, 0, stream>>>(xtq, xtc, wqb, wkb, wvb,
                                             qtb, ktb, vcb);

    hipMemsetAsync(attn_map, 0, (size_t)BATCH * NTOK * sizeof(float), stream);

    attn<<<dim3(768), blk, 0, stream>>>(qtb, ktb, vcb, omid, attn_map);

    o_proj<<<dim3(768), blk, 0, stream>>>(wob, omid, bo, out);
}